// Round 1
// baseline (278.820 us; speedup 1.0000x reference)
//
#include <hip/hip_runtime.h>
#include <hip/hip_bf16.h>

// N=1024 rois, DF=1024, DK=DV=DG=64, NR=16 heads.
// ws layout: [0,64MB) scores/g f32 [16][1024][1024]
//            [64MB,96MB) P bf16 [16][1024][1024]
//            [96MB) Q bf16 [16][1024][64], [98MB) K bf16, [100MB) Vt bf16 [16][64][1024],
//            [102MB) Y bf16 [1024][1024]

typedef __bf16 bf16_t;
typedef __attribute__((ext_vector_type(8))) __bf16 bf16x8;
typedef __attribute__((ext_vector_type(4))) __bf16 bf16x4;
typedef __attribute__((ext_vector_type(4))) float f32x4;

__device__ inline bf16_t f2b(float f) {
    unsigned u = __builtin_bit_cast(unsigned, f);
    unsigned r = u + 0x7fffu + ((u >> 16) & 1u);
    unsigned short h = (unsigned short)(r >> 16);
    return __builtin_bit_cast(bf16_t, h);
}

// ---------------- g = log(max(relu(pe @ Wg^T + bg), 1e-6)), head-major ----------------
__global__ __launch_bounds__(256) void g_kernel(const float* __restrict__ pe,
                                                const float* __restrict__ Wg,
                                                const float* __restrict__ bg,
                                                float* __restrict__ g) {
    __shared__ float wg_s[16][64];
    __shared__ float bg_s[16];
    __shared__ float tile[64][65];  // pad to break bank conflicts on column reads
    const int t = threadIdx.x;
    for (int i = t; i < 1024; i += 256) wg_s[i >> 6][i & 63] = Wg[i];
    if (t < 16) bg_s[t] = bg[t];
    const long rowbase = (long)blockIdx.x * 64;  // flat row = i*1024 + j
    const float4* src = (const float4*)(pe + rowbase * 64);
#pragma unroll
    for (int p = 0; p < 4; p++) {
        float4 v = src[p * 256 + t];
        int f = (p * 256 + t) * 4;
        int r = f >> 6, d = f & 63;
        tile[r][d] = v.x; tile[r][d + 1] = v.y; tile[r][d + 2] = v.z; tile[r][d + 3] = v.w;
    }
    __syncthreads();
    const int r = t & 63, hb = (t >> 6) * 4;
    float a0 = bg_s[hb], a1 = bg_s[hb + 1], a2 = bg_s[hb + 2], a3 = bg_s[hb + 3];
#pragma unroll
    for (int d = 0; d < 64; d++) {
        float pv = tile[r][d];
        a0 += pv * wg_s[hb][d];
        a1 += pv * wg_s[hb + 1][d];
        a2 += pv * wg_s[hb + 2][d];
        a3 += pv * wg_s[hb + 3][d];
    }
    const float LOGMIN = -13.815510557964274f;
    float o0 = (a0 > 1e-6f) ? __logf(a0) : LOGMIN;
    float o1 = (a1 > 1e-6f) ? __logf(a1) : LOGMIN;
    float o2 = (a2 > 1e-6f) ? __logf(a2) : LOGMIN;
    float o3 = (a3 > 1e-6f) ? __logf(a3) : LOGMIN;
    g[(long)(hb + 0) * 1048576 + rowbase + r] = o0;
    g[(long)(hb + 1) * 1048576 + rowbase + r] = o1;
    g[(long)(hb + 2) * 1048576 + rowbase + r] = o2;
    g[(long)(hb + 3) * 1048576 + rowbase + r] = o3;
}

// ---------------- generic 64x64-tile bf16 MFMA GEMM: C = A[MxK] @ B[NxK]^T ----------------
// MODE 0: proj -> bf16 [h][n][dk] (+bias)      MODE 1: proj -> bf16 [h][dv][n] (+bias)
// MODE 2: scores RMW f32 [z][row][col] += acc  MODE 3: Y bf16 [row][z*64+col]
// MODE 4: out f32 = acc + bias[col] + x[row][col]
template <typename TA, typename TB, int MODE>
__global__ __launch_bounds__(256) void gemm_k(const TA* __restrict__ A, int lda, long strideAz,
                                              const TB* __restrict__ B, int ldb, long strideBz,
                                              int Ksz,
                                              const float* __restrict__ bias,
                                              void* __restrict__ outp,
                                              const float* __restrict__ extra) {
    __shared__ bf16_t As[2][64][40];
    __shared__ bf16_t Bs[2][64][40];
    const int t = threadIdx.x;
    const int bx = blockIdx.x, by = blockIdx.y, bz = blockIdx.z;
    A += (long)bz * strideAz;
    B += (long)bz * strideBz;
    const int m0 = by * 64, n0 = bx * 64;
    const int lr = t >> 2, lq = t & 3;

    auto stageA = [&](int buf, int k0) {
        const TA* p = A + (long)(m0 + lr) * lda + k0 + lq * 8;
        bf16x8 v;
        if constexpr (sizeof(TA) == 4) {
            float4 u0 = *(const float4*)p;
            float4 u1 = *(const float4*)(p + 4);
            v[0] = f2b(u0.x); v[1] = f2b(u0.y); v[2] = f2b(u0.z); v[3] = f2b(u0.w);
            v[4] = f2b(u1.x); v[5] = f2b(u1.y); v[6] = f2b(u1.z); v[7] = f2b(u1.w);
        } else {
            v = *(const bf16x8*)p;
        }
        *(bf16x8*)&As[buf][lr][lq * 8] = v;
    };
    auto stageB = [&](int buf, int k0) {
        const TB* p = B + (long)(n0 + lr) * ldb + k0 + lq * 8;
        bf16x8 v;
        if constexpr (sizeof(TB) == 4) {
            float4 u0 = *(const float4*)p;
            float4 u1 = *(const float4*)(p + 4);
            v[0] = f2b(u0.x); v[1] = f2b(u0.y); v[2] = f2b(u0.z); v[3] = f2b(u0.w);
            v[4] = f2b(u1.x); v[5] = f2b(u1.y); v[6] = f2b(u1.z); v[7] = f2b(u1.w);
        } else {
            v = *(const bf16x8*)p;
        }
        *(bf16x8*)&Bs[buf][lr][lq * 8] = v;
    };

    const int wid = t >> 6, lane = t & 63;
    const int wm = (wid >> 1) * 32, wn = (wid & 1) * 32;
    const int ml = lane & 15, kl = (lane >> 4) * 8;
    f32x4 acc[2][2] = {};
    const int nk = Ksz >> 5;

    stageA(0, 0);
    stageB(0, 0);
    __syncthreads();
    for (int kt = 0; kt < nk; kt++) {
        const int buf = kt & 1;
        if (kt + 1 < nk) { stageA(buf ^ 1, (kt + 1) * 32); stageB(buf ^ 1, (kt + 1) * 32); }
        bf16x8 a0 = *(const bf16x8*)&As[buf][wm + ml][kl];
        bf16x8 a1 = *(const bf16x8*)&As[buf][wm + 16 + ml][kl];
        bf16x8 b0 = *(const bf16x8*)&Bs[buf][wn + ml][kl];
        bf16x8 b1 = *(const bf16x8*)&Bs[buf][wn + 16 + ml][kl];
        acc[0][0] = __builtin_amdgcn_mfma_f32_16x16x32_bf16(a0, b0, acc[0][0], 0, 0, 0);
        acc[0][1] = __builtin_amdgcn_mfma_f32_16x16x32_bf16(a0, b1, acc[0][1], 0, 0, 0);
        acc[1][0] = __builtin_amdgcn_mfma_f32_16x16x32_bf16(a1, b0, acc[1][0], 0, 0, 0);
        acc[1][1] = __builtin_amdgcn_mfma_f32_16x16x32_bf16(a1, b1, acc[1][1], 0, 0, 0);
        __syncthreads();
    }

#pragma unroll
    for (int mt = 0; mt < 2; mt++)
#pragma unroll
        for (int nt = 0; nt < 2; nt++) {
            f32x4 v = acc[mt][nt];
            const int rbase = m0 + wm + mt * 16 + ((lane >> 4) << 2);
            const int col = n0 + wn + nt * 16 + (lane & 15);
#pragma unroll
            for (int r = 0; r < 4; r++) {
                const int row = rbase + r;
                float val = v[r];
                if constexpr (MODE == 0) {
                    val += bias[col];
                    int h = col >> 6, dk = col & 63;
                    ((bf16_t*)outp)[((long)h << 16) + ((long)row << 6) + dk] = f2b(val);
                } else if constexpr (MODE == 1) {
                    val += bias[col];
                    int h = col >> 6, dv = col & 63;
                    ((bf16_t*)outp)[((long)h << 16) + ((long)dv << 10) + row] = f2b(val);
                } else if constexpr (MODE == 2) {
                    float* s = (float*)outp + ((long)bz << 20) + ((long)row << 10) + col;
                    *s = *s + val;
                } else if constexpr (MODE == 3) {
                    ((bf16_t*)outp)[((long)row << 10) + (bz << 6) + col] = f2b(val);
                } else {
                    long idx = ((long)row << 10) + col;
                    ((float*)outp)[idx] = val + bias[col] + extra[idx];
                }
            }
        }
}

// ---------------- row softmax: f32 scores -> bf16 P ----------------
__global__ __launch_bounds__(256) void softmax_k(const float* __restrict__ S,
                                                 bf16_t* __restrict__ P) {
    const int row = blockIdx.x, t = threadIdx.x;
    const float4 v = ((const float4*)(S + ((long)row << 10)))[t];
    float mx = fmaxf(fmaxf(v.x, v.y), fmaxf(v.z, v.w));
#pragma unroll
    for (int off = 32; off; off >>= 1) mx = fmaxf(mx, __shfl_xor(mx, off));
    __shared__ float rmax[4], rsum[4];
    if ((t & 63) == 0) rmax[t >> 6] = mx;
    __syncthreads();
    mx = fmaxf(fmaxf(rmax[0], rmax[1]), fmaxf(rmax[2], rmax[3]));
    float e0 = __expf(v.x - mx), e1 = __expf(v.y - mx), e2 = __expf(v.z - mx), e3 = __expf(v.w - mx);
    float s = e0 + e1 + e2 + e3;
#pragma unroll
    for (int off = 32; off; off >>= 1) s += __shfl_xor(s, off);
    if ((t & 63) == 0) rsum[t >> 6] = s;
    __syncthreads();
    float inv = 1.0f / (rsum[0] + rsum[1] + rsum[2] + rsum[3]);
    bf16x4 o;
    o[0] = f2b(e0 * inv); o[1] = f2b(e1 * inv); o[2] = f2b(e2 * inv); o[3] = f2b(e3 * inv);
    *(bf16x4*)(P + ((long)row << 10) + t * 4) = o;
}

extern "C" void kernel_launch(void* const* d_in, const int* in_sizes, int n_in,
                              void* d_out, int out_size, void* d_ws, size_t ws_size,
                              hipStream_t stream) {
    const float* x  = (const float*)d_in[0];
    const float* pe = (const float*)d_in[1];
    const float* Wq = (const float*)d_in[2];
    const float* bq = (const float*)d_in[3];
    const float* Wk = (const float*)d_in[4];
    const float* bk = (const float*)d_in[5];
    const float* Wv = (const float*)d_in[6];
    const float* bv = (const float*)d_in[7];
    const float* Wg = (const float*)d_in[8];
    const float* bg = (const float*)d_in[9];
    const float* Wy = (const float*)d_in[10];
    const float* by = (const float*)d_in[11];

    char* ws = (char*)d_ws;
    float*  scores = (float*)ws;                               // 64 MB (g, then +=QK^T)
    bf16_t* P      = (bf16_t*)(ws + (64ul << 20));             // 32 MB
    bf16_t* Qb     = (bf16_t*)(ws + (96ul << 20));             // 2 MB
    bf16_t* Kb     = (bf16_t*)(ws + (98ul << 20));             // 2 MB
    bf16_t* Vt     = (bf16_t*)(ws + (100ul << 20));            // 2 MB
    bf16_t* Yb     = (bf16_t*)(ws + (102ul << 20));            // 2 MB

    g_kernel<<<16384, 256, 0, stream>>>(pe, Wg, bg, scores);
    gemm_k<float, float, 0><<<dim3(16, 16, 1), 256, 0, stream>>>(x, 1024, 0, Wq, 1024, 0, 1024, bq, Qb, nullptr);
    gemm_k<float, float, 0><<<dim3(16, 16, 1), 256, 0, stream>>>(x, 1024, 0, Wk, 1024, 0, 1024, bk, Kb, nullptr);
    gemm_k<float, float, 1><<<dim3(16, 16, 1), 256, 0, stream>>>(x, 1024, 0, Wv, 1024, 0, 1024, bv, Vt, nullptr);
    gemm_k<bf16_t, bf16_t, 2><<<dim3(16, 16, 16), 256, 0, stream>>>(Qb, 64, 65536, Kb, 64, 65536, 64, nullptr, scores, nullptr);
    softmax_k<<<16384, 256, 0, stream>>>(scores, P);
    gemm_k<bf16_t, bf16_t, 3><<<dim3(1, 16, 16), 256, 0, stream>>>(P, 1024, 1048576, Vt, 1024, 65536, 1024, nullptr, Yb, nullptr);
    gemm_k<bf16_t, float, 4><<<dim3(16, 16, 1), 256, 0, stream>>>(Yb, 1024, 0, Wy, 1024, 0, 1024, by, d_out, x);
}

// Round 3
// 223.118 us; speedup vs baseline: 1.2497x; 1.2497x over previous
//
#include <hip/hip_runtime.h>
#include <hip/hip_bf16.h>

// N=1024 rois, DF=1024, DK=DV=DG=64, NR=16 heads.
// ws: [0,32MB) w=max(relu(pe@Wg^T+bg),1e-6) f16 [16][1024][1024]
//     [32MB) Q bf16 [16][1024][64]; [34MB) K same; [36MB) Vt bf16 [16][64][1024]; [38MB) Y bf16 [1024][1024]

typedef __bf16 bf16_t;
typedef _Float16 f16_t;
typedef __attribute__((ext_vector_type(8))) __bf16 bf16x8;
typedef __attribute__((ext_vector_type(8))) _Float16 f16x8;
typedef __attribute__((ext_vector_type(4))) float f32x4;

__device__ inline bf16_t f2b(float f) {
    unsigned u = __builtin_bit_cast(unsigned, f);
    unsigned r = u + 0x7fffu + ((u >> 16) & 1u);
    unsigned short h = (unsigned short)(r >> 16);
    return __builtin_bit_cast(bf16_t, h);
}

// ---- w = max(relu(pe @ Wg^T + bg), 1e-6) as f16, head-major [h][i][j].
// Round-1-PROVEN scalar structure (bisect: isolates round-2's MFMA wg as the suspect).
__global__ __launch_bounds__(256) void g_scalar_kernel(const float* __restrict__ pe,
                                                       const float* __restrict__ Wg,
                                                       const float* __restrict__ bg,
                                                       f16_t* __restrict__ Wout) {
    __shared__ float wg_s[16][64];
    __shared__ float bg_s[16];
    __shared__ float tile[64][65];  // pad to break bank conflicts on column reads
    const int t = threadIdx.x;
    for (int i = t; i < 1024; i += 256) wg_s[i >> 6][i & 63] = Wg[i];
    if (t < 16) bg_s[t] = bg[t];
    const long rowbase = (long)blockIdx.x * 64;  // flat row = i*1024 + j
    const float4* src = (const float4*)(pe + rowbase * 64);
#pragma unroll
    for (int p = 0; p < 4; p++) {
        float4 v = src[p * 256 + t];
        int f = (p * 256 + t) * 4;
        int r = f >> 6, d = f & 63;
        tile[r][d] = v.x; tile[r][d + 1] = v.y; tile[r][d + 2] = v.z; tile[r][d + 3] = v.w;
    }
    __syncthreads();
    const int r = t & 63, hb = (t >> 6) * 4;
    float a0 = bg_s[hb], a1 = bg_s[hb + 1], a2 = bg_s[hb + 2], a3 = bg_s[hb + 3];
#pragma unroll
    for (int d = 0; d < 64; d++) {
        float pv = tile[r][d];
        a0 += pv * wg_s[hb][d];
        a1 += pv * wg_s[hb + 1][d];
        a2 += pv * wg_s[hb + 2][d];
        a3 += pv * wg_s[hb + 3][d];
    }
    // w = max(relu(a), 1e-6) == max(a, 1e-6); softmax(qk+log w) == w*e^qk/sum
    Wout[(long)(hb + 0) * 1048576 + rowbase + r] = (f16_t)fmaxf(a0, 1e-6f);
    Wout[(long)(hb + 1) * 1048576 + rowbase + r] = (f16_t)fmaxf(a1, 1e-6f);
    Wout[(long)(hb + 2) * 1048576 + rowbase + r] = (f16_t)fmaxf(a2, 1e-6f);
    Wout[(long)(hb + 3) * 1048576 + rowbase + r] = (f16_t)fmaxf(a3, 1e-6f);
}

// ---- generic 64x64-tile bf16 MFMA GEMM: C = A[MxK] @ B[NxK]^T ----
// MODE 0: -> bf16 [h][n][dk] (+bias)   MODE 1: -> bf16 [h][dv][n] (+bias)
// MODE 4: f32 out = acc + bias[col] + x[row][col]
template <typename TA, typename TB, int MODE>
__global__ __launch_bounds__(256) void gemm_k(const TA* __restrict__ A, int lda,
                                              const TB* __restrict__ B, int ldb,
                                              int Ksz,
                                              const float* __restrict__ bias,
                                              void* __restrict__ outp,
                                              const float* __restrict__ extra) {
    __shared__ bf16_t As[2][64][40];
    __shared__ bf16_t Bs[2][64][40];
    const int t = threadIdx.x;
    const int m0 = blockIdx.y * 64, n0 = blockIdx.x * 64;
    const int lr = t >> 2, lq = t & 3;

    auto stageA = [&](int buf, int k0) {
        const TA* p = A + (long)(m0 + lr) * lda + k0 + lq * 8;
        bf16x8 v;
        if constexpr (sizeof(TA) == 4) {
            float4 u0 = *(const float4*)p;
            float4 u1 = *(const float4*)(p + 4);
            v[0] = f2b(u0.x); v[1] = f2b(u0.y); v[2] = f2b(u0.z); v[3] = f2b(u0.w);
            v[4] = f2b(u1.x); v[5] = f2b(u1.y); v[6] = f2b(u1.z); v[7] = f2b(u1.w);
        } else {
            v = *(const bf16x8*)p;
        }
        *(bf16x8*)&As[buf][lr][lq * 8] = v;
    };
    auto stageB = [&](int buf, int k0) {
        const TB* p = B + (long)(n0 + lr) * ldb + k0 + lq * 8;
        bf16x8 v;
        if constexpr (sizeof(TB) == 4) {
            float4 u0 = *(const float4*)p;
            float4 u1 = *(const float4*)(p + 4);
            v[0] = f2b(u0.x); v[1] = f2b(u0.y); v[2] = f2b(u0.z); v[3] = f2b(u0.w);
            v[4] = f2b(u1.x); v[5] = f2b(u1.y); v[6] = f2b(u1.z); v[7] = f2b(u1.w);
        } else {
            v = *(const bf16x8*)p;
        }
        *(bf16x8*)&Bs[buf][lr][lq * 8] = v;
    };

    const int wid = t >> 6, lane = t & 63;
    const int wm = (wid >> 1) * 32, wn = (wid & 1) * 32;
    const int ml = lane & 15, kl = (lane >> 4) * 8;
    f32x4 acc[2][2] = {};
    const int nk = Ksz >> 5;

    stageA(0, 0);
    stageB(0, 0);
    __syncthreads();
    for (int kt = 0; kt < nk; kt++) {
        const int buf = kt & 1;
        if (kt + 1 < nk) { stageA(buf ^ 1, (kt + 1) * 32); stageB(buf ^ 1, (kt + 1) * 32); }
        bf16x8 a0 = *(const bf16x8*)&As[buf][wm + ml][kl];
        bf16x8 a1 = *(const bf16x8*)&As[buf][wm + 16 + ml][kl];
        bf16x8 b0 = *(const bf16x8*)&Bs[buf][wn + ml][kl];
        bf16x8 b1 = *(const bf16x8*)&Bs[buf][wn + 16 + ml][kl];
        acc[0][0] = __builtin_amdgcn_mfma_f32_16x16x32_bf16(a0, b0, acc[0][0], 0, 0, 0);
        acc[0][1] = __builtin_amdgcn_mfma_f32_16x16x32_bf16(a0, b1, acc[0][1], 0, 0, 0);
        acc[1][0] = __builtin_amdgcn_mfma_f32_16x16x32_bf16(a1, b0, acc[1][0], 0, 0, 0);
        acc[1][1] = __builtin_amdgcn_mfma_f32_16x16x32_bf16(a1, b1, acc[1][1], 0, 0, 0);
        __syncthreads();
    }

#pragma unroll
    for (int mt = 0; mt < 2; mt++)
#pragma unroll
        for (int nt = 0; nt < 2; nt++) {
            f32x4 v = acc[mt][nt];
            const int rbase = m0 + wm + mt * 16 + ((lane >> 4) << 2);
            const int col = n0 + wn + nt * 16 + (lane & 15);
#pragma unroll
            for (int r = 0; r < 4; r++) {
                const int row = rbase + r;
                float val = v[r];
                if constexpr (MODE == 0) {
                    val += bias[col];
                    int h = col >> 6, dk = col & 63;
                    ((bf16_t*)outp)[((long)h << 16) + ((long)row << 6) + dk] = f2b(val);
                } else if constexpr (MODE == 1) {
                    val += bias[col];
                    int h = col >> 6, dv = col & 63;
                    ((bf16_t*)outp)[((long)h << 16) + ((long)dv << 10) + row] = f2b(val);
                } else {
                    long idx = ((long)row << 10) + col;
                    ((float*)outp)[idx] = val + bias[col] + extra[idx];
                }
            }
        }
}

// ---- fused attention: per (qtile64, head): S=QK^T, p=exp(S)*w, O=pV, O/=sum ----
__global__ __launch_bounds__(256) void attn_kernel(const bf16_t* __restrict__ Q,
                                                   const bf16_t* __restrict__ K,
                                                   const bf16_t* __restrict__ Vt,
                                                   const f16_t* __restrict__ Wf,
                                                   bf16_t* __restrict__ Y) {
    __shared__ bf16_t Qs[64][72];
    __shared__ bf16_t Ks[2][64][72];
    __shared__ bf16_t Vts[2][64][72];
    __shared__ f16_t  Ws[2][64][72];
    __shared__ bf16_t Ps[4][16][72];

    const int qt = blockIdx.x, h = blockIdx.y;
    const int t = threadIdx.x;
    const int w = t >> 6, lane = t & 63;
    const int ml = lane & 15, kq = lane >> 4;
    const int q0 = qt << 6;
    const int sr = t >> 2, sc = (t & 3) << 4;

    const bf16_t* Kh = K + ((long)h << 16);
    const bf16_t* Vh = Vt + ((long)h << 16);
    const f16_t*  Wh = Wf + ((long)h << 20) + ((long)(q0 + sr) << 10);

    {   // stage Q + tile 0
        const bf16_t* src = Q + ((long)h << 16) + ((long)(q0 + sr) << 6) + sc;
        *(bf16x8*)&Qs[sr][sc]     = *(const bf16x8*)src;
        *(bf16x8*)&Qs[sr][sc + 8] = *(const bf16x8*)(src + 8);
        const bf16_t* ks = Kh + ((long)sr << 6) + sc;
        *(bf16x8*)&Ks[0][sr][sc]     = *(const bf16x8*)ks;
        *(bf16x8*)&Ks[0][sr][sc + 8] = *(const bf16x8*)(ks + 8);
        const bf16_t* vs = Vh + ((long)sr << 10) + sc;
        *(bf16x8*)&Vts[0][sr][sc]     = *(const bf16x8*)vs;
        *(bf16x8*)&Vts[0][sr][sc + 8] = *(const bf16x8*)(vs + 8);
        const f16_t* gs = Wh + sc;
        *(f16x8*)&Ws[0][sr][sc]     = *(const f16x8*)gs;
        *(f16x8*)&Ws[0][sr][sc + 8] = *(const f16x8*)(gs + 8);
    }
    __syncthreads();

    const bf16x8 aq0 = *(const bf16x8*)&Qs[(w << 4) + ml][kq * 8];
    const bf16x8 aq1 = *(const bf16x8*)&Qs[(w << 4) + ml][32 + kq * 8];

    f32x4 O[4] = {};
    float lsum[4] = {0.f, 0.f, 0.f, 0.f};

    int buf = 0;
    for (int kt = 0; kt < 16; kt++) {
        bf16x8 rk0, rk1, rv0, rv1;
        f16x8 rw0, rw1;
        const bool pf = (kt < 15);
        if (pf) {  // issue next-tile loads early (T14): latency hides under compute
            const int k0 = (kt + 1) << 6;
            const bf16_t* ks = Kh + ((long)(k0 + sr) << 6) + sc;
            rk0 = *(const bf16x8*)ks; rk1 = *(const bf16x8*)(ks + 8);
            const bf16_t* vs = Vh + ((long)sr << 10) + k0 + sc;
            rv0 = *(const bf16x8*)vs; rv1 = *(const bf16x8*)(vs + 8);
            const f16_t* gs = Wh + k0 + sc;
            rw0 = *(const f16x8*)gs; rw1 = *(const f16x8*)(gs + 8);
        }

        // QK^T: wave tile = 16 q-rows x 64 keys
        f32x4 s[4] = {};
#pragma unroll
        for (int c = 0; c < 4; c++) {
            bf16x8 bk0 = *(const bf16x8*)&Ks[buf][(c << 4) + ml][kq * 8];
            bf16x8 bk1 = *(const bf16x8*)&Ks[buf][(c << 4) + ml][32 + kq * 8];
            s[c] = __builtin_amdgcn_mfma_f32_16x16x32_bf16(aq0, bk0, s[c], 0, 0, 0);
            s[c] = __builtin_amdgcn_mfma_f32_16x16x32_bf16(aq1, bk1, s[c], 0, 0, 0);
        }
        // p = exp(s) * w   (softmax(qk+log w) == w*e^qk/sum; no max needed: |s|<~50)
#pragma unroll
        for (int c = 0; c < 4; c++) {
#pragma unroll
            for (int r = 0; r < 4; r++) {
                float wv = (float)Ws[buf][(w << 4) + (kq << 2) + r][(c << 4) + ml];
                float p = __expf(s[c][r]) * wv;
                lsum[r] += p;
                Ps[w][(kq << 2) + r][(c << 4) + ml] = f2b(p);
            }
        }
        // PV: A = P (per-wave LDS transpose), B = Vt rows (dv)
        const bf16x8 pa0 = *(const bf16x8*)&Ps[w][ml][kq * 8];
        const bf16x8 pa1 = *(const bf16x8*)&Ps[w][ml][32 + kq * 8];
#pragma unroll
        for (int c = 0; c < 4; c++) {
            bf16x8 v0 = *(const bf16x8*)&Vts[buf][(c << 4) + ml][kq * 8];
            bf16x8 v1 = *(const bf16x8*)&Vts[buf][(c << 4) + ml][32 + kq * 8];
            O[c] = __builtin_amdgcn_mfma_f32_16x16x32_bf16(pa0, v0, O[c], 0, 0, 0);
            O[c] = __builtin_amdgcn_mfma_f32_16x16x32_bf16(pa1, v1, O[c], 0, 0, 0);
        }

        if (pf) {  // write-late staging into the other buffer
            const int nb = buf ^ 1;
            *(bf16x8*)&Ks[nb][sr][sc]      = rk0;
            *(bf16x8*)&Ks[nb][sr][sc + 8]  = rk1;
            *(bf16x8*)&Vts[nb][sr][sc]     = rv0;
            *(bf16x8*)&Vts[nb][sr][sc + 8] = rv1;
            *(f16x8*)&Ws[nb][sr][sc]       = rw0;
            *(f16x8*)&Ws[nb][sr][sc + 8]   = rw1;
        }
        __syncthreads();
        buf ^= 1;
    }

#pragma unroll
    for (int r = 0; r < 4; r++) {
        float v = lsum[r];
        v += __shfl_xor(v, 1); v += __shfl_xor(v, 2);
        v += __shfl_xor(v, 4); v += __shfl_xor(v, 8);
        lsum[r] = 1.0f / v;
    }
    const int rowb = q0 + (w << 4) + (kq << 2);
    const int colb = (h << 6) + ml;
#pragma unroll
    for (int c = 0; c < 4; c++)
#pragma unroll
        for (int r = 0; r < 4; r++)
            Y[((long)(rowb + r) << 10) + colb + (c << 4)] = f2b(O[c][r] * lsum[r]);
}

extern "C" void kernel_launch(void* const* d_in, const int* in_sizes, int n_in,
                              void* d_out, int out_size, void* d_ws, size_t ws_size,
                              hipStream_t stream) {
    const float* x  = (const float*)d_in[0];
    const float* pe = (const float*)d_in[1];
    const float* Wq = (const float*)d_in[2];
    const float* bq = (const float*)d_in[3];
    const float* Wk = (const float*)d_in[4];
    const float* bk = (const float*)d_in[5];
    const float* Wv = (const float*)d_in[6];
    const float* bv = (const float*)d_in[7];
    const float* Wg = (const float*)d_in[8];
    const float* bg = (const float*)d_in[9];
    const float* Wy = (const float*)d_in[10];
    const float* by = (const float*)d_in[11];

    char* ws = (char*)d_ws;
    f16_t*  Wf = (f16_t*)ws;                         // 32 MB
    bf16_t* Qb = (bf16_t*)(ws + (32ul << 20));       // 2 MB
    bf16_t* Kb = (bf16_t*)(ws + (34ul << 20));       // 2 MB
    bf16_t* Vb = (bf16_t*)(ws + (36ul << 20));       // 2 MB
    bf16_t* Yb = (bf16_t*)(ws + (38ul << 20));       // 2 MB

    g_scalar_kernel<<<16384, 256, 0, stream>>>(pe, Wg, bg, Wf);
    gemm_k<float, float, 0><<<dim3(16, 16), 256, 0, stream>>>(x, 1024, Wq, 1024, 1024, bq, Qb, nullptr);
    gemm_k<float, float, 0><<<dim3(16, 16), 256, 0, stream>>>(x, 1024, Wk, 1024, 1024, bk, Kb, nullptr);
    gemm_k<float, float, 1><<<dim3(16, 16), 256, 0, stream>>>(x, 1024, Wv, 1024, 1024, bv, Vb, nullptr);
    attn_kernel<<<dim3(16, 16), 256, 0, stream>>>(Qb, Kb, Vb, Wf, Yb);
    gemm_k<bf16_t, float, 4><<<dim3(16, 16), 256, 0, stream>>>(Yb, 1024, Wy, 1024, 1024, by, d_out, x);
}

// Round 5
// 145.478 us; speedup vs baseline: 1.9166x; 1.5337x over previous
//
#include <hip/hip_runtime.h>
#include <hip/hip_bf16.h>

// N=1024 rois, DF=1024, DK=DV=DG=64, NR=16 heads.
// ws: [0,32MB) w=max(relu(pe@Wg^T+bg),1e-6) f16 [16][1024][1024]
//     [32MB) Q bf16 [16][1024][64]; [34MB) K same; [36MB) Vt bf16 [16][64][1024]; [38MB) Y bf16 [1024][1024]

typedef __bf16 bf16_t;
typedef _Float16 f16_t;
typedef __attribute__((ext_vector_type(8))) __bf16 bf16x8;
typedef __attribute__((ext_vector_type(8))) _Float16 f16x8;
typedef __attribute__((ext_vector_type(4))) float f32x4;

__device__ inline bf16_t f2b(float f) {
    unsigned u = __builtin_bit_cast(unsigned, f);
    unsigned r = u + 0x7fffu + ((u >> 16) & 1u);
    unsigned short h = (unsigned short)(r >> 16);
    return __builtin_bit_cast(bf16_t, h);
}

// ---- w = max(relu(pe @ Wg^T + bg), 1e-6) as f16, head-major [h][i][j].
// f32 math (precision cliff at relu boundary demands it — round-2 lesson).
// LDS-issue fix: b128 XOR-swizzled tile reads (16/thread, conflict-free even
// distribution) + wave-uniform s_load for Wg/bg (zero wg LDS traffic).
__global__ __launch_bounds__(256) void g_kernel2(const float* __restrict__ pe,
                                                 const float* __restrict__ Wg,
                                                 const float* __restrict__ bg,
                                                 f16_t* __restrict__ Wout) {
    __shared__ float4 tile4[64][16];  // row r, chunk c stored at slot c ^ (r&15)
    const int t = threadIdx.x;
    const long rowbase = (long)blockIdx.x * 64;  // flat pair index = i*1024 + j
    const float4* src = (const float4*)(pe + rowbase * 64);
#pragma unroll
    for (int p = 0; p < 4; p++) {
        float4 v = src[p * 256 + t];
        int fi = p * 256 + t;            // float4 index: row = fi>>4, chunk = fi&15
        int r = fi >> 4, c = fi & 15;
        tile4[r][c ^ (r & 15)] = v;
    }
    __syncthreads();
    const int r = t & 63;
    const int hbu = __builtin_amdgcn_readfirstlane((t >> 6) << 2);  // wave-uniform head base
    const float* wg0 = Wg + hbu * 64;
    const float* wg1 = wg0 + 64;
    const float* wg2 = wg0 + 128;
    const float* wg3 = wg0 + 192;
    float a0 = bg[hbu + 0], a1 = bg[hbu + 1], a2 = bg[hbu + 2], a3 = bg[hbu + 3];
#pragma unroll
    for (int dq = 0; dq < 16; dq++) {
        float4 pv = tile4[r][dq ^ (r & 15)];
        float4 w0 = *(const float4*)(wg0 + dq * 4);
        float4 w1 = *(const float4*)(wg1 + dq * 4);
        float4 w2 = *(const float4*)(wg2 + dq * 4);
        float4 w3 = *(const float4*)(wg3 + dq * 4);
        a0 += pv.x * w0.x + pv.y * w0.y + pv.z * w0.z + pv.w * w0.w;
        a1 += pv.x * w1.x + pv.y * w1.y + pv.z * w1.z + pv.w * w1.w;
        a2 += pv.x * w2.x + pv.y * w2.y + pv.z * w2.z + pv.w * w2.w;
        a3 += pv.x * w3.x + pv.y * w3.y + pv.z * w3.z + pv.w * w3.w;
    }
    // w = max(relu(a), 1e-6) == max(a, 1e-6); softmax(qk+log w) == w*e^qk/sum
    Wout[(long)(hbu + 0) * 1048576 + rowbase + r] = (f16_t)fmaxf(a0, 1e-6f);
    Wout[(long)(hbu + 1) * 1048576 + rowbase + r] = (f16_t)fmaxf(a1, 1e-6f);
    Wout[(long)(hbu + 2) * 1048576 + rowbase + r] = (f16_t)fmaxf(a2, 1e-6f);
    Wout[(long)(hbu + 3) * 1048576 + rowbase + r] = (f16_t)fmaxf(a3, 1e-6f);
}

// ---- fused Q/K/V projections: z selects weight/bias/output. C = x @ W^T + b ----
// z=0 -> Q bf16 [h][n][dk], z=1 -> K bf16 [h][n][dk], z=2 -> V bf16 [h][dv][n]
__global__ __launch_bounds__(256) void proj3_k(const float* __restrict__ x,
                                               const float* __restrict__ Wq, const float* __restrict__ bq, bf16_t* __restrict__ Qb,
                                               const float* __restrict__ Wk, const float* __restrict__ bk, bf16_t* __restrict__ Kb,
                                               const float* __restrict__ Wv, const float* __restrict__ bv, bf16_t* __restrict__ Vb) {
    __shared__ bf16_t As[2][64][40];
    __shared__ bf16_t Bs[2][64][40];
    const int z = blockIdx.z;
    const float* B = (z == 0) ? Wq : (z == 1) ? Wk : Wv;
    const float* bias = (z == 0) ? bq : (z == 1) ? bk : bv;
    bf16_t* outp = (z == 0) ? Qb : (z == 1) ? Kb : Vb;

    const int t = threadIdx.x;
    const int m0 = blockIdx.y * 64, n0 = blockIdx.x * 64;
    const int lr = t >> 2, lq = t & 3;

    auto stage = [&](bf16_t (*dst)[64][40], const float* __restrict__ Sp, int ld, int row0, int buf, int k0) {
        const float* p = Sp + (long)(row0 + lr) * ld + k0 + lq * 8;
        float4 u0 = *(const float4*)p;
        float4 u1 = *(const float4*)(p + 4);
        bf16x8 v;
        v[0] = f2b(u0.x); v[1] = f2b(u0.y); v[2] = f2b(u0.z); v[3] = f2b(u0.w);
        v[4] = f2b(u1.x); v[5] = f2b(u1.y); v[6] = f2b(u1.z); v[7] = f2b(u1.w);
        *(bf16x8*)&dst[buf][lr][lq * 8] = v;
    };

    const int wid = t >> 6, lane = t & 63;
    const int wm = (wid >> 1) * 32, wn = (wid & 1) * 32;
    const int ml = lane & 15, kl = (lane >> 4) * 8;
    f32x4 acc[2][2] = {};

    stage(As, x, 1024, m0, 0, 0);
    stage(Bs, B, 1024, n0, 0, 0);
    __syncthreads();
    for (int kt = 0; kt < 32; kt++) {
        const int buf = kt & 1;
        if (kt + 1 < 32) { stage(As, x, 1024, m0, buf ^ 1, (kt + 1) * 32); stage(Bs, B, 1024, n0, buf ^ 1, (kt + 1) * 32); }
        bf16x8 a0 = *(const bf16x8*)&As[buf][wm + ml][kl];
        bf16x8 a1 = *(const bf16x8*)&As[buf][wm + 16 + ml][kl];
        bf16x8 b0 = *(const bf16x8*)&Bs[buf][wn + ml][kl];
        bf16x8 b1 = *(const bf16x8*)&Bs[buf][wn + 16 + ml][kl];
        acc[0][0] = __builtin_amdgcn_mfma_f32_16x16x32_bf16(a0, b0, acc[0][0], 0, 0, 0);
        acc[0][1] = __builtin_amdgcn_mfma_f32_16x16x32_bf16(a0, b1, acc[0][1], 0, 0, 0);
        acc[1][0] = __builtin_amdgcn_mfma_f32_16x16x32_bf16(a1, b0, acc[1][0], 0, 0, 0);
        acc[1][1] = __builtin_amdgcn_mfma_f32_16x16x32_bf16(a1, b1, acc[1][1], 0, 0, 0);
        __syncthreads();
    }

#pragma unroll
    for (int mt = 0; mt < 2; mt++)
#pragma unroll
        for (int nt = 0; nt < 2; nt++) {
            f32x4 v = acc[mt][nt];
            const int rbase = m0 + wm + mt * 16 + ((lane >> 4) << 2);
            const int col = n0 + wn + nt * 16 + (lane & 15);
#pragma unroll
            for (int r = 0; r < 4; r++) {
                const int row = rbase + r;
                float val = v[r] + bias[col];
                int h = col >> 6, d = col & 63;
                if (z < 2) outp[((long)h << 16) + ((long)row << 6) + d] = f2b(val);
                else       outp[((long)h << 16) + ((long)d << 10) + row] = f2b(val);
            }
        }
}

// ---- final GEMM: out f32 = Yb @ Wy^T + by + x ----
__global__ __launch_bounds__(256) void gemmY_k(const bf16_t* __restrict__ A,
                                               const float* __restrict__ Bw,
                                               const float* __restrict__ bias,
                                               float* __restrict__ outp,
                                               const float* __restrict__ extra) {
    __shared__ bf16_t As[2][64][40];
    __shared__ bf16_t Bs[2][64][40];
    const int t = threadIdx.x;
    const int m0 = blockIdx.y * 64, n0 = blockIdx.x * 64;
    const int lr = t >> 2, lq = t & 3;

    auto stageA = [&](int buf, int k0) {
        const bf16_t* p = A + (long)(m0 + lr) * 1024 + k0 + lq * 8;
        *(bf16x8*)&As[buf][lr][lq * 8] = *(const bf16x8*)p;
    };
    auto stageB = [&](int buf, int k0) {
        const float* p = Bw + (long)(n0 + lr) * 1024 + k0 + lq * 8;
        float4 u0 = *(const float4*)p;
        float4 u1 = *(const float4*)(p + 4);
        bf16x8 v;
        v[0] = f2b(u0.x); v[1] = f2b(u0.y); v[2] = f2b(u0.z); v[3] = f2b(u0.w);
        v[4] = f2b(u1.x); v[5] = f2b(u1.y); v[6] = f2b(u1.z); v[7] = f2b(u1.w);
        *(bf16x8*)&Bs[buf][lr][lq * 8] = v;
    };

    const int wid = t >> 6, lane = t & 63;
    const int wm = (wid >> 1) * 32, wn = (wid & 1) * 32;
    const int ml = lane & 15, kl = (lane >> 4) * 8;
    f32x4 acc[2][2] = {};

    stageA(0, 0);
    stageB(0, 0);
    __syncthreads();
    for (int kt = 0; kt < 32; kt++) {
        const int buf = kt & 1;
        if (kt + 1 < 32) { stageA(buf ^ 1, (kt + 1) * 32); stageB(buf ^ 1, (kt + 1) * 32); }
        bf16x8 a0 = *(const bf16x8*)&As[buf][wm + ml][kl];
        bf16x8 a1 = *(const bf16x8*)&As[buf][wm + 16 + ml][kl];
        bf16x8 b0 = *(const bf16x8*)&Bs[buf][wn + ml][kl];
        bf16x8 b1 = *(const bf16x8*)&Bs[buf][wn + 16 + ml][kl];
        acc[0][0] = __builtin_amdgcn_mfma_f32_16x16x32_bf16(a0, b0, acc[0][0], 0, 0, 0);
        acc[0][1] = __builtin_amdgcn_mfma_f32_16x16x32_bf16(a0, b1, acc[0][1], 0, 0, 0);
        acc[1][0] = __builtin_amdgcn_mfma_f32_16x16x32_bf16(a1, b0, acc[1][0], 0, 0, 0);
        acc[1][1] = __builtin_amdgcn_mfma_f32_16x16x32_bf16(a1, b1, acc[1][1], 0, 0, 0);
        __syncthreads();
    }

#pragma unroll
    for (int mt = 0; mt < 2; mt++)
#pragma unroll
        for (int nt = 0; nt < 2; nt++) {
            f32x4 v = acc[mt][nt];
            const int rbase = m0 + wm + mt * 16 + ((lane >> 4) << 2);
            const int col = n0 + wn + nt * 16 + (lane & 15);
#pragma unroll
            for (int r = 0; r < 4; r++) {
                const int row = rbase + r;
                long idx = ((long)row << 10) + col;
                outp[idx] = v[r] + bias[col] + extra[idx];
            }
        }
}

// ---- fused attention: per (qtile64, head): S=QK^T, p=exp(S)*w, O=pV, O/=sum ----
__global__ __launch_bounds__(256) void attn_kernel(const bf16_t* __restrict__ Q,
                                                   const bf16_t* __restrict__ K,
                                                   const bf16_t* __restrict__ Vt,
                                                   const f16_t* __restrict__ Wf,
                                                   bf16_t* __restrict__ Y) {
    __shared__ bf16_t Qs[64][72];
    __shared__ bf16_t Ks[2][64][72];
    __shared__ bf16_t Vts[2][64][72];
    __shared__ f16_t  Ws[2][64][72];
    __shared__ bf16_t Ps[4][16][72];

    const int qt = blockIdx.x, h = blockIdx.y;
    const int t = threadIdx.x;
    const int w = t >> 6, lane = t & 63;
    const int ml = lane & 15, kq = lane >> 4;
    const int q0 = qt << 6;
    const int sr = t >> 2, sc = (t & 3) << 4;

    const bf16_t* Kh = K + ((long)h << 16);
    const bf16_t* Vh = Vt + ((long)h << 16);
    const f16_t*  Wh = Wf + ((long)h << 20) + ((long)(q0 + sr) << 10);

    {   // stage Q + tile 0
        const bf16_t* src = Q + ((long)h << 16) + ((long)(q0 + sr) << 6) + sc;
        *(bf16x8*)&Qs[sr][sc]     = *(const bf16x8*)src;
        *(bf16x8*)&Qs[sr][sc + 8] = *(const bf16x8*)(src + 8);
        const bf16_t* ks = Kh + ((long)sr << 6) + sc;
        *(bf16x8*)&Ks[0][sr][sc]     = *(const bf16x8*)ks;
        *(bf16x8*)&Ks[0][sr][sc + 8] = *(const bf16x8*)(ks + 8);
        const bf16_t* vs = Vh + ((long)sr << 10) + sc;
        *(bf16x8*)&Vts[0][sr][sc]     = *(const bf16x8*)vs;
        *(bf16x8*)&Vts[0][sr][sc + 8] = *(const bf16x8*)(vs + 8);
        const f16_t* gs = Wh + sc;
        *(f16x8*)&Ws[0][sr][sc]     = *(const f16x8*)gs;
        *(f16x8*)&Ws[0][sr][sc + 8] = *(const f16x8*)(gs + 8);
    }
    __syncthreads();

    const bf16x8 aq0 = *(const bf16x8*)&Qs[(w << 4) + ml][kq * 8];
    const bf16x8 aq1 = *(const bf16x8*)&Qs[(w << 4) + ml][32 + kq * 8];

    f32x4 O[4] = {};
    float lsum[4] = {0.f, 0.f, 0.f, 0.f};

    int buf = 0;
    for (int kt = 0; kt < 16; kt++) {
        bf16x8 rk0, rk1, rv0, rv1;
        f16x8 rw0, rw1;
        const bool pf = (kt < 15);
        if (pf) {  // issue next-tile loads early (T14): latency hides under compute
            const int k0 = (kt + 1) << 6;
            const bf16_t* ks = Kh + ((long)(k0 + sr) << 6) + sc;
            rk0 = *(const bf16x8*)ks; rk1 = *(const bf16x8*)(ks + 8);
            const bf16_t* vs = Vh + ((long)sr << 10) + k0 + sc;
            rv0 = *(const bf16x8*)vs; rv1 = *(const bf16x8*)(vs + 8);
            const f16_t* gs = Wh + k0 + sc;
            rw0 = *(const f16x8*)gs; rw1 = *(const f16x8*)(gs + 8);
        }

        // QK^T: wave tile = 16 q-rows x 64 keys
        f32x4 s[4] = {};
#pragma unroll
        for (int c = 0; c < 4; c++) {
            bf16x8 bk0 = *(const bf16x8*)&Ks[buf][(c << 4) + ml][kq * 8];
            bf16x8 bk1 = *(const bf16x8*)&Ks[buf][(c << 4) + ml][32 + kq * 8];
            s[c] = __builtin_amdgcn_mfma_f32_16x16x32_bf16(aq0, bk0, s[c], 0, 0, 0);
            s[c] = __builtin_amdgcn_mfma_f32_16x16x32_bf16(aq1, bk1, s[c], 0, 0, 0);
        }
        // p = exp(s) * w   (softmax(qk+log w) == w*e^qk/sum; no max needed: |s|<~50)
#pragma unroll
        for (int c = 0; c < 4; c++) {
#pragma unroll
            for (int r = 0; r < 4; r++) {
                float wv = (float)Ws[buf][(w << 4) + (kq << 2) + r][(c << 4) + ml];
                float p = __expf(s[c][r]) * wv;
                lsum[r] += p;
                Ps[w][(kq << 2) + r][(c << 4) + ml] = f2b(p);
            }
        }
        // PV: A = P (per-wave LDS transpose), B = Vt rows (dv)
        const bf16x8 pa0 = *(const bf16x8*)&Ps[w][ml][kq * 8];
        const bf16x8 pa1 = *(const bf16x8*)&Ps[w][ml][32 + kq * 8];
#pragma unroll
        for (int c = 0; c < 4; c++) {
            bf16x8 v0 = *(const bf16x8*)&Vts[buf][(c << 4) + ml][kq * 8];
            bf16x8 v1 = *(const bf16x8*)&Vts[buf][(c << 4) + ml][32 + kq * 8];
            O[c] = __builtin_amdgcn_mfma_f32_16x16x32_bf16(pa0, v0, O[c], 0, 0, 0);
            O[c] = __builtin_amdgcn_mfma_f32_16x16x32_bf16(pa1, v1, O[c], 0, 0, 0);
        }

        if (pf) {  // write-late staging into the other buffer
            const int nb = buf ^ 1;
            *(bf16x8*)&Ks[nb][sr][sc]      = rk0;
            *(bf16x8*)&Ks[nb][sr][sc + 8]  = rk1;
            *(bf16x8*)&Vts[nb][sr][sc]     = rv0;
            *(bf16x8*)&Vts[nb][sr][sc + 8] = rv1;
            *(f16x8*)&Ws[nb][sr][sc]       = rw0;
            *(f16x8*)&Ws[nb][sr][sc + 8]   = rw1;
        }
        __syncthreads();
        buf ^= 1;
    }

#pragma unroll
    for (int r = 0; r < 4; r++) {
        float v = lsum[r];
        v += __shfl_xor(v, 1); v += __shfl_xor(v, 2);
        v += __shfl_xor(v, 4); v += __shfl_xor(v, 8);
        lsum[r] = 1.0f / v;
    }
    const int rowb = q0 + (w << 4) + (kq << 2);
    const int colb = (h << 6) + ml;
#pragma unroll
    for (int c = 0; c < 4; c++)
#pragma unroll
        for (int r = 0; r < 4; r++)
            Y[((long)(rowb + r) << 10) + colb + (c << 4)] = f2b(O[c][r] * lsum[r]);
}

extern "C" void kernel_launch(void* const* d_in, const int* in_sizes, int n_in,
                              void* d_out, int out_size, void* d_ws, size_t ws_size,
                              hipStream_t stream) {
    const float* x  = (const float*)d_in[0];
    const float* pe = (const float*)d_in[1];
    const float* Wq = (const float*)d_in[2];
    const float* bq = (const float*)d_in[3];
    const float* Wk = (const float*)d_in[4];
    const float* bk = (const float*)d_in[5];
    const float* Wv = (const float*)d_in[6];
    const float* bv = (const float*)d_in[7];
    const float* Wg = (const float*)d_in[8];
    const float* bg = (const float*)d_in[9];
    const float* Wy = (const float*)d_in[10];
    const float* by = (const float*)d_in[11];

    char* ws = (char*)d_ws;
    f16_t*  Wf = (f16_t*)ws;                         // 32 MB
    bf16_t* Qb = (bf16_t*)(ws + (32ul << 20));       // 2 MB
    bf16_t* Kb = (bf16_t*)(ws + (34ul << 20));       // 2 MB
    bf16_t* Vb = (bf16_t*)(ws + (36ul << 20));       // 2 MB
    bf16_t* Yb = (bf16_t*)(ws + (38ul << 20));       // 2 MB

    g_kernel2<<<16384, 256, 0, stream>>>(pe, Wg, bg, Wf);
    proj3_k<<<dim3(16, 16, 3), 256, 0, stream>>>(x, Wq, bq, Qb, Wk, bk, Kb, Wv, bv, Vb);
    attn_kernel<<<dim3(16, 16), 256, 0, stream>>>(Qb, Kb, Vb, Wf, Yb);
    gemmY_k<<<dim3(16, 16), 256, 0, stream>>>(Yb, Wy, by, (float*)d_out, x);
}

// Round 6
// 129.584 us; speedup vs baseline: 2.1517x; 1.1227x over previous
//
#include <hip/hip_runtime.h>
#include <hip/hip_bf16.h>

// N=1024 rois, DF=1024, DK=DV=DG=64, NR=16 heads.
// ws: [0,32MB) w=max(relu(pe@Wg^T+bg),1e-6) f16 [16][1024][1024]
//     [32MB) Q bf16 [16][1024][64]; [34MB) K same; [36MB) Vt bf16 [16][64][1024]; [38MB) Y bf16 [1024][1024]

typedef __bf16 bf16_t;
typedef _Float16 f16_t;
typedef __attribute__((ext_vector_type(8))) __bf16 bf16x8;
typedef __attribute__((ext_vector_type(8))) _Float16 f16x8;
typedef __attribute__((ext_vector_type(4))) float f32x4;

__device__ inline bf16_t f2b(float f) {
    unsigned u = __builtin_bit_cast(unsigned, f);
    unsigned r = u + 0x7fffu + ((u >> 16) & 1u);
    unsigned short h = (unsigned short)(r >> 16);
    return __builtin_bit_cast(bf16_t, h);
}

// ---- fused (g + Q/K/V projections) heterogeneous kernel ----
// blocks [0,768): proj z=bid/256 (0:Q,1:K,2:V), 16x16 tile grid
// blocks [768,768+16384): w = max(relu(pe@Wg^T+bg),1e-6) -> f16 head-major
// proj blocks first so their MFMA work overlaps g's HBM streaming.
__global__ __launch_bounds__(256) void fused_g_proj_k(
        const float* __restrict__ pe, const float* __restrict__ Wg, const float* __restrict__ bg,
        f16_t* __restrict__ Wout,
        const float* __restrict__ x,
        const float* __restrict__ Wq, const float* __restrict__ bq, bf16_t* __restrict__ Qb,
        const float* __restrict__ Wk, const float* __restrict__ bk, bf16_t* __restrict__ Kb,
        const float* __restrict__ Wv, const float* __restrict__ bv, bf16_t* __restrict__ Vb) {
    __shared__ float4 tile4[64][16];        // g path (16 KB)
    __shared__ bf16_t As[2][64][40];        // proj path (10 KB)
    __shared__ bf16_t Bs[2][64][40];        // proj path (10 KB)
    const int bid = blockIdx.x;
    const int t = threadIdx.x;

    if (bid < 768) {
        // ================= projection GEMM: C = x @ W^T + b =================
        const int z = bid >> 8, rem = bid & 255;
        const float* B = (z == 0) ? Wq : (z == 1) ? Wk : Wv;
        const float* bias = (z == 0) ? bq : (z == 1) ? bk : bv;
        bf16_t* outp = (z == 0) ? Qb : (z == 1) ? Kb : Vb;
        const int m0 = (rem >> 4) * 64, n0 = (rem & 15) * 64;
        const int lr = t >> 2, lq = t & 3;

        auto stage = [&](bf16_t (*dst)[64][40], const float* __restrict__ Sp, int row0, int buf, int k0) {
            const float* p = Sp + (long)(row0 + lr) * 1024 + k0 + lq * 8;
            float4 u0 = *(const float4*)p;
            float4 u1 = *(const float4*)(p + 4);
            bf16x8 v;
            v[0] = f2b(u0.x); v[1] = f2b(u0.y); v[2] = f2b(u0.z); v[3] = f2b(u0.w);
            v[4] = f2b(u1.x); v[5] = f2b(u1.y); v[6] = f2b(u1.z); v[7] = f2b(u1.w);
            *(bf16x8*)&dst[buf][lr][lq * 8] = v;
        };

        const int wid = t >> 6, lane = t & 63;
        const int wm = (wid >> 1) * 32, wn = (wid & 1) * 32;
        const int ml = lane & 15, kl = (lane >> 4) * 8;
        f32x4 acc[2][2] = {};

        stage(As, x, m0, 0, 0);
        stage(Bs, B, n0, 0, 0);
        __syncthreads();
        for (int kt = 0; kt < 32; kt++) {
            const int buf = kt & 1;
            if (kt + 1 < 32) { stage(As, x, m0, buf ^ 1, (kt + 1) * 32); stage(Bs, B, n0, buf ^ 1, (kt + 1) * 32); }
            bf16x8 a0 = *(const bf16x8*)&As[buf][wm + ml][kl];
            bf16x8 a1 = *(const bf16x8*)&As[buf][wm + 16 + ml][kl];
            bf16x8 b0 = *(const bf16x8*)&Bs[buf][wn + ml][kl];
            bf16x8 b1 = *(const bf16x8*)&Bs[buf][wn + 16 + ml][kl];
            acc[0][0] = __builtin_amdgcn_mfma_f32_16x16x32_bf16(a0, b0, acc[0][0], 0, 0, 0);
            acc[0][1] = __builtin_amdgcn_mfma_f32_16x16x32_bf16(a0, b1, acc[0][1], 0, 0, 0);
            acc[1][0] = __builtin_amdgcn_mfma_f32_16x16x32_bf16(a1, b0, acc[1][0], 0, 0, 0);
            acc[1][1] = __builtin_amdgcn_mfma_f32_16x16x32_bf16(a1, b1, acc[1][1], 0, 0, 0);
            __syncthreads();
        }

#pragma unroll
        for (int mt = 0; mt < 2; mt++)
#pragma unroll
            for (int nt = 0; nt < 2; nt++) {
                f32x4 v = acc[mt][nt];
                const int rbase = m0 + wm + mt * 16 + ((lane >> 4) << 2);
                const int col = n0 + wn + nt * 16 + (lane & 15);
#pragma unroll
                for (int r = 0; r < 4; r++) {
                    const int row = rbase + r;
                    float val = v[r] + bias[col];
                    int h = col >> 6, d = col & 63;
                    if (z < 2) outp[((long)h << 16) + ((long)row << 6) + d] = f2b(val);
                    else       outp[((long)h << 16) + ((long)d << 10) + row] = f2b(val);
                }
            }
    } else {
        // ================= g: w = max(relu(pe@Wg^T+bg), 1e-6) =================
        // f32 math (precision cliff at relu boundary — round-2 lesson).
        const long rowbase = (long)(bid - 768) * 64;  // flat pair index = i*1024 + j
        const float4* src = (const float4*)(pe + rowbase * 64);
#pragma unroll
        for (int p = 0; p < 4; p++) {
            float4 v = src[p * 256 + t];
            int fi = p * 256 + t;            // float4 index: row = fi>>4, chunk = fi&15
            int r = fi >> 4, c = fi & 15;
            tile4[r][c ^ (r & 15)] = v;      // XOR swizzle: conflict-free b128 r/w
        }
        __syncthreads();
        const int r = t & 63;
        const int hbu = __builtin_amdgcn_readfirstlane((t >> 6) << 2);  // wave-uniform head base
        const float* wg0 = Wg + hbu * 64;
        const float* wg1 = wg0 + 64;
        const float* wg2 = wg0 + 128;
        const float* wg3 = wg0 + 192;
        float a0 = bg[hbu + 0], a1 = bg[hbu + 1], a2 = bg[hbu + 2], a3 = bg[hbu + 3];
#pragma unroll
        for (int dq = 0; dq < 16; dq++) {
            float4 pv = tile4[r][dq ^ (r & 15)];
            float4 w0 = *(const float4*)(wg0 + dq * 4);
            float4 w1 = *(const float4*)(wg1 + dq * 4);
            float4 w2 = *(const float4*)(wg2 + dq * 4);
            float4 w3 = *(const float4*)(wg3 + dq * 4);
            a0 += pv.x * w0.x + pv.y * w0.y + pv.z * w0.z + pv.w * w0.w;
            a1 += pv.x * w1.x + pv.y * w1.y + pv.z * w1.z + pv.w * w1.w;
            a2 += pv.x * w2.x + pv.y * w2.y + pv.z * w2.z + pv.w * w2.w;
            a3 += pv.x * w3.x + pv.y * w3.y + pv.z * w3.z + pv.w * w3.w;
        }
        // w = max(relu(a), 1e-6) == max(a, 1e-6); softmax(qk+log w) == w*e^qk/sum
        Wout[(long)(hbu + 0) * 1048576 + rowbase + r] = (f16_t)fmaxf(a0, 1e-6f);
        Wout[(long)(hbu + 1) * 1048576 + rowbase + r] = (f16_t)fmaxf(a1, 1e-6f);
        Wout[(long)(hbu + 2) * 1048576 + rowbase + r] = (f16_t)fmaxf(a2, 1e-6f);
        Wout[(long)(hbu + 3) * 1048576 + rowbase + r] = (f16_t)fmaxf(a3, 1e-6f);
    }
}

// ---- final GEMM: out f32 = Yb @ Wy^T + by + x ----
__global__ __launch_bounds__(256) void gemmY_k(const bf16_t* __restrict__ A,
                                               const float* __restrict__ Bw,
                                               const float* __restrict__ bias,
                                               float* __restrict__ outp,
                                               const float* __restrict__ extra) {
    __shared__ bf16_t As[2][64][40];
    __shared__ bf16_t Bs[2][64][40];
    const int t = threadIdx.x;
    const int m0 = blockIdx.y * 64, n0 = blockIdx.x * 64;
    const int lr = t >> 2, lq = t & 3;

    auto stageA = [&](int buf, int k0) {
        const bf16_t* p = A + (long)(m0 + lr) * 1024 + k0 + lq * 8;
        *(bf16x8*)&As[buf][lr][lq * 8] = *(const bf16x8*)p;
    };
    auto stageB = [&](int buf, int k0) {
        const float* p = Bw + (long)(n0 + lr) * 1024 + k0 + lq * 8;
        float4 u0 = *(const float4*)p;
        float4 u1 = *(const float4*)(p + 4);
        bf16x8 v;
        v[0] = f2b(u0.x); v[1] = f2b(u0.y); v[2] = f2b(u0.z); v[3] = f2b(u0.w);
        v[4] = f2b(u1.x); v[5] = f2b(u1.y); v[6] = f2b(u1.z); v[7] = f2b(u1.w);
        *(bf16x8*)&Bs[buf][lr][lq * 8] = v;
    };

    const int wid = t >> 6, lane = t & 63;
    const int wm = (wid >> 1) * 32, wn = (wid & 1) * 32;
    const int ml = lane & 15, kl = (lane >> 4) * 8;
    f32x4 acc[2][2] = {};

    stageA(0, 0);
    stageB(0, 0);
    __syncthreads();
    for (int kt = 0; kt < 32; kt++) {
        const int buf = kt & 1;
        if (kt + 1 < 32) { stageA(buf ^ 1, (kt + 1) * 32); stageB(buf ^ 1, (kt + 1) * 32); }
        bf16x8 a0 = *(const bf16x8*)&As[buf][wm + ml][kl];
        bf16x8 a1 = *(const bf16x8*)&As[buf][wm + 16 + ml][kl];
        bf16x8 b0 = *(const bf16x8*)&Bs[buf][wn + ml][kl];
        bf16x8 b1 = *(const bf16x8*)&Bs[buf][wn + 16 + ml][kl];
        acc[0][0] = __builtin_amdgcn_mfma_f32_16x16x32_bf16(a0, b0, acc[0][0], 0, 0, 0);
        acc[0][1] = __builtin_amdgcn_mfma_f32_16x16x32_bf16(a0, b1, acc[0][1], 0, 0, 0);
        acc[1][0] = __builtin_amdgcn_mfma_f32_16x16x32_bf16(a1, b0, acc[1][0], 0, 0, 0);
        acc[1][1] = __builtin_amdgcn_mfma_f32_16x16x32_bf16(a1, b1, acc[1][1], 0, 0, 0);
        __syncthreads();
    }

#pragma unroll
    for (int mt = 0; mt < 2; mt++)
#pragma unroll
        for (int nt = 0; nt < 2; nt++) {
            f32x4 v = acc[mt][nt];
            const int rbase = m0 + wm + mt * 16 + ((lane >> 4) << 2);
            const int col = n0 + wn + nt * 16 + (lane & 15);
#pragma unroll
            for (int r = 0; r < 4; r++) {
                const int row = rbase + r;
                long idx = ((long)row << 10) + col;
                outp[idx] = v[r] + bias[col] + extra[idx];
            }
        }
}

// ---- fused attention: per (qtile64, head): S=QK^T, p=exp(S)*w, O=pV, O/=sum ----
__global__ __launch_bounds__(256) void attn_kernel(const bf16_t* __restrict__ Q,
                                                   const bf16_t* __restrict__ K,
                                                   const bf16_t* __restrict__ Vt,
                                                   const f16_t* __restrict__ Wf,
                                                   bf16_t* __restrict__ Y) {
    __shared__ bf16_t Qs[64][72];
    __shared__ bf16_t Ks[2][64][72];
    __shared__ bf16_t Vts[2][64][72];
    __shared__ f16_t  Ws[2][64][72];
    __shared__ bf16_t Ps[4][16][72];

    const int qt = blockIdx.x, h = blockIdx.y;
    const int t = threadIdx.x;
    const int w = t >> 6, lane = t & 63;
    const int ml = lane & 15, kq = lane >> 4;
    const int q0 = qt << 6;
    const int sr = t >> 2, sc = (t & 3) << 4;

    const bf16_t* Kh = K + ((long)h << 16);
    const bf16_t* Vh = Vt + ((long)h << 16);
    const f16_t*  Wh = Wf + ((long)h << 20) + ((long)(q0 + sr) << 10);

    {   // stage Q + tile 0
        const bf16_t* src = Q + ((long)h << 16) + ((long)(q0 + sr) << 6) + sc;
        *(bf16x8*)&Qs[sr][sc]     = *(const bf16x8*)src;
        *(bf16x8*)&Qs[sr][sc + 8] = *(const bf16x8*)(src + 8);
        const bf16_t* ks = Kh + ((long)sr << 6) + sc;
        *(bf16x8*)&Ks[0][sr][sc]     = *(const bf16x8*)ks;
        *(bf16x8*)&Ks[0][sr][sc + 8] = *(const bf16x8*)(ks + 8);
        const bf16_t* vs = Vh + ((long)sr << 10) + sc;
        *(bf16x8*)&Vts[0][sr][sc]     = *(const bf16x8*)vs;
        *(bf16x8*)&Vts[0][sr][sc + 8] = *(const bf16x8*)(vs + 8);
        const f16_t* gs = Wh + sc;
        *(f16x8*)&Ws[0][sr][sc]     = *(const f16x8*)gs;
        *(f16x8*)&Ws[0][sr][sc + 8] = *(const f16x8*)(gs + 8);
    }
    __syncthreads();

    const bf16x8 aq0 = *(const bf16x8*)&Qs[(w << 4) + ml][kq * 8];
    const bf16x8 aq1 = *(const bf16x8*)&Qs[(w << 4) + ml][32 + kq * 8];

    f32x4 O[4] = {};
    float lsum[4] = {0.f, 0.f, 0.f, 0.f};

    int buf = 0;
    for (int kt = 0; kt < 16; kt++) {
        bf16x8 rk0, rk1, rv0, rv1;
        f16x8 rw0, rw1;
        const bool pf = (kt < 15);
        if (pf) {  // issue next-tile loads early (T14): latency hides under compute
            const int k0 = (kt + 1) << 6;
            const bf16_t* ks = Kh + ((long)(k0 + sr) << 6) + sc;
            rk0 = *(const bf16x8*)ks; rk1 = *(const bf16x8*)(ks + 8);
            const bf16_t* vs = Vh + ((long)sr << 10) + k0 + sc;
            rv0 = *(const bf16x8*)vs; rv1 = *(const bf16x8*)(vs + 8);
            const f16_t* gs = Wh + k0 + sc;
            rw0 = *(const f16x8*)gs; rw1 = *(const f16x8*)(gs + 8);
        }

        // QK^T: wave tile = 16 q-rows x 64 keys
        f32x4 s[4] = {};
#pragma unroll
        for (int c = 0; c < 4; c++) {
            bf16x8 bk0 = *(const bf16x8*)&Ks[buf][(c << 4) + ml][kq * 8];
            bf16x8 bk1 = *(const bf16x8*)&Ks[buf][(c << 4) + ml][32 + kq * 8];
            s[c] = __builtin_amdgcn_mfma_f32_16x16x32_bf16(aq0, bk0, s[c], 0, 0, 0);
            s[c] = __builtin_amdgcn_mfma_f32_16x16x32_bf16(aq1, bk1, s[c], 0, 0, 0);
        }
        // p = exp(s) * w   (softmax(qk+log w) == w*e^qk/sum; no max needed: |s|<~50)
#pragma unroll
        for (int c = 0; c < 4; c++) {
#pragma unroll
            for (int r = 0; r < 4; r++) {
                float wv = (float)Ws[buf][(w << 4) + (kq << 2) + r][(c << 4) + ml];
                float p = __expf(s[c][r]) * wv;
                lsum[r] += p;
                Ps[w][(kq << 2) + r][(c << 4) + ml] = f2b(p);
            }
        }
        // PV: A = P (per-wave LDS transpose), B = Vt rows (dv)
        const bf16x8 pa0 = *(const bf16x8*)&Ps[w][ml][kq * 8];
        const bf16x8 pa1 = *(const bf16x8*)&Ps[w][ml][32 + kq * 8];
#pragma unroll
        for (int c = 0; c < 4; c++) {
            bf16x8 v0 = *(const bf16x8*)&Vts[buf][(c << 4) + ml][kq * 8];
            bf16x8 v1 = *(const bf16x8*)&Vts[buf][(c << 4) + ml][32 + kq * 8];
            O[c] = __builtin_amdgcn_mfma_f32_16x16x32_bf16(pa0, v0, O[c], 0, 0, 0);
            O[c] = __builtin_amdgcn_mfma_f32_16x16x32_bf16(pa1, v1, O[c], 0, 0, 0);
        }

        if (pf) {  // write-late staging into the other buffer
            const int nb = buf ^ 1;
            *(bf16x8*)&Ks[nb][sr][sc]      = rk0;
            *(bf16x8*)&Ks[nb][sr][sc + 8]  = rk1;
            *(bf16x8*)&Vts[nb][sr][sc]     = rv0;
            *(bf16x8*)&Vts[nb][sr][sc + 8] = rv1;
            *(f16x8*)&Ws[nb][sr][sc]       = rw0;
            *(f16x8*)&Ws[nb][sr][sc + 8]   = rw1;
        }
        __syncthreads();
        buf ^= 1;
    }

#pragma unroll
    for (int r = 0; r < 4; r++) {
        float v = lsum[r];
        v += __shfl_xor(v, 1); v += __shfl_xor(v, 2);
        v += __shfl_xor(v, 4); v += __shfl_xor(v, 8);
        lsum[r] = 1.0f / v;
    }
    const int rowb = q0 + (w << 4) + (kq << 2);
    const int colb = (h << 6) + ml;
#pragma unroll
    for (int c = 0; c < 4; c++)
#pragma unroll
        for (int r = 0; r < 4; r++)
            Y[((long)(rowb + r) << 10) + colb + (c << 4)] = f2b(O[c][r] * lsum[r]);
}

extern "C" void kernel_launch(void* const* d_in, const int* in_sizes, int n_in,
                              void* d_out, int out_size, void* d_ws, size_t ws_size,
                              hipStream_t stream) {
    const float* x  = (const float*)d_in[0];
    const float* pe = (const float*)d_in[1];
    const float* Wq = (const float*)d_in[2];
    const float* bq = (const float*)d_in[3];
    const float* Wk = (const float*)d_in[4];
    const float* bk = (const float*)d_in[5];
    const float* Wv = (const float*)d_in[6];
    const float* bv = (const float*)d_in[7];
    const float* Wg = (const float*)d_in[8];
    const float* bg = (const float*)d_in[9];
    const float* Wy = (const float*)d_in[10];
    const float* by = (const float*)d_in[11];

    char* ws = (char*)d_ws;
    f16_t*  Wf = (f16_t*)ws;                         // 32 MB
    bf16_t* Qb = (bf16_t*)(ws + (32ul << 20));       // 2 MB
    bf16_t* Kb = (bf16_t*)(ws + (34ul << 20));       // 2 MB
    bf16_t* Vb = (bf16_t*)(ws + (36ul << 20));       // 2 MB
    bf16_t* Yb = (bf16_t*)(ws + (38ul << 20));       // 2 MB

    fused_g_proj_k<<<768 + 16384, 256, 0, stream>>>(pe, Wg, bg, Wf,
                                                    x, Wq, bq, Qb, Wk, bk, Kb, Wv, bv, Vb);
    attn_kernel<<<dim3(16, 16), 256, 0, stream>>>(Qb, Kb, Vb, Wf, Yb);
    gemmY_k<<<dim3(16, 16), 256, 0, stream>>>(Yb, Wy, by, (float*)d_out, x);
}

// Round 7
// 127.786 us; speedup vs baseline: 2.1819x; 1.0141x over previous
//
#include <hip/hip_runtime.h>
#include <hip/hip_bf16.h>

// N=1024 rois, DF=1024, DK=DV=DG=64, NR=16 heads.
// ws: [0,32MB) w=max(relu(pe@Wg^T+bg),1e-6) f16 [16][1024][1024]
//     [32MB) Q bf16 [16][1024][64]; [34MB) K same; [36MB) Vt bf16 [16][64][1024]; [38MB) Y bf16 [1024][1024]

typedef __bf16 bf16_t;
typedef _Float16 f16_t;
typedef __attribute__((ext_vector_type(8))) __bf16 bf16x8;
typedef __attribute__((ext_vector_type(8))) _Float16 f16x8;
typedef __attribute__((ext_vector_type(4))) float f32x4;

__device__ inline bf16_t f2b(float f) {
    unsigned u = __builtin_bit_cast(unsigned, f);
    unsigned r = u + 0x7fffu + ((u >> 16) & 1u);
    unsigned short h = (unsigned short)(r >> 16);
    return __builtin_bit_cast(bf16_t, h);
}

// ---- fused (g + Q/K/V projections) heterogeneous kernel ----
// blocks [0,768): proj z=bid/256 (0:Q,1:K,2:V), 16x16 tile grid
// blocks [768,768+16384): w = max(relu(pe@Wg^T+bg),1e-6) -> f16 head-major
// g-path: pe row in VGPRs (read LDS once), one head per pass so Wg row is a
// small uniform (SGPR) footprint hoisted out of the FMA chain (round-6 stall fix).
__global__ __launch_bounds__(256) void fused_g_proj_k(
        const float* __restrict__ pe, const float* __restrict__ Wg, const float* __restrict__ bg,
        f16_t* __restrict__ Wout,
        const float* __restrict__ x,
        const float* __restrict__ Wq, const float* __restrict__ bq, bf16_t* __restrict__ Qb,
        const float* __restrict__ Wk, const float* __restrict__ bk, bf16_t* __restrict__ Kb,
        const float* __restrict__ Wv, const float* __restrict__ bv, bf16_t* __restrict__ Vb) {
    __shared__ float4 tile4[64][16];        // g path (16 KB)
    __shared__ bf16_t As[2][64][40];        // proj path (10 KB)
    __shared__ bf16_t Bs[2][64][40];        // proj path (10 KB)
    const int bid = blockIdx.x;
    const int t = threadIdx.x;

    if (bid < 768) {
        // ================= projection GEMM: C = x @ W^T + b =================
        const int z = bid >> 8, rem = bid & 255;
        const float* B = (z == 0) ? Wq : (z == 1) ? Wk : Wv;
        const float* bias = (z == 0) ? bq : (z == 1) ? bk : bv;
        bf16_t* outp = (z == 0) ? Qb : (z == 1) ? Kb : Vb;
        const int m0 = (rem >> 4) * 64, n0 = (rem & 15) * 64;
        const int lr = t >> 2, lq = t & 3;

        auto stage = [&](bf16_t (*dst)[64][40], const float* __restrict__ Sp, int row0, int buf, int k0) {
            const float* p = Sp + (long)(row0 + lr) * 1024 + k0 + lq * 8;
            float4 u0 = *(const float4*)p;
            float4 u1 = *(const float4*)(p + 4);
            bf16x8 v;
            v[0] = f2b(u0.x); v[1] = f2b(u0.y); v[2] = f2b(u0.z); v[3] = f2b(u0.w);
            v[4] = f2b(u1.x); v[5] = f2b(u1.y); v[6] = f2b(u1.z); v[7] = f2b(u1.w);
            *(bf16x8*)&dst[buf][lr][lq * 8] = v;
        };

        const int wid = t >> 6, lane = t & 63;
        const int wm = (wid >> 1) * 32, wn = (wid & 1) * 32;
        const int ml = lane & 15, kl = (lane >> 4) * 8;
        f32x4 acc[2][2] = {};

        stage(As, x, m0, 0, 0);
        stage(Bs, B, n0, 0, 0);
        __syncthreads();
        for (int kt = 0; kt < 32; kt++) {
            const int buf = kt & 1;
            if (kt + 1 < 32) { stage(As, x, m0, buf ^ 1, (kt + 1) * 32); stage(Bs, B, n0, buf ^ 1, (kt + 1) * 32); }
            bf16x8 a0 = *(const bf16x8*)&As[buf][wm + ml][kl];
            bf16x8 a1 = *(const bf16x8*)&As[buf][wm + 16 + ml][kl];
            bf16x8 b0 = *(const bf16x8*)&Bs[buf][wn + ml][kl];
            bf16x8 b1 = *(const bf16x8*)&Bs[buf][wn + 16 + ml][kl];
            acc[0][0] = __builtin_amdgcn_mfma_f32_16x16x32_bf16(a0, b0, acc[0][0], 0, 0, 0);
            acc[0][1] = __builtin_amdgcn_mfma_f32_16x16x32_bf16(a0, b1, acc[0][1], 0, 0, 0);
            acc[1][0] = __builtin_amdgcn_mfma_f32_16x16x32_bf16(a1, b0, acc[1][0], 0, 0, 0);
            acc[1][1] = __builtin_amdgcn_mfma_f32_16x16x32_bf16(a1, b1, acc[1][1], 0, 0, 0);
            __syncthreads();
        }

#pragma unroll
        for (int mt = 0; mt < 2; mt++)
#pragma unroll
            for (int nt = 0; nt < 2; nt++) {
                f32x4 v = acc[mt][nt];
                const int rbase = m0 + wm + mt * 16 + ((lane >> 4) << 2);
                const int col = n0 + wn + nt * 16 + (lane & 15);
#pragma unroll
                for (int r = 0; r < 4; r++) {
                    const int row = rbase + r;
                    float val = v[r] + bias[col];
                    int h = col >> 6, d = col & 63;
                    if (z < 2) outp[((long)h << 16) + ((long)row << 6) + d] = f2b(val);
                    else       outp[((long)h << 16) + ((long)d << 10) + row] = f2b(val);
                }
            }
    } else {
        // ================= g: w = max(relu(pe@Wg^T+bg), 1e-6) =================
        // f32 math (precision cliff at relu boundary — round-2 lesson).
        const long rowbase = (long)(bid - 768) * 64;  // flat pair index = i*1024 + j
        const float4* src = (const float4*)(pe + rowbase * 64);
#pragma unroll
        for (int p = 0; p < 4; p++) {
            float4 v = src[p * 256 + t];
            int fi = p * 256 + t;            // float4 index: row = fi>>4, chunk = fi&15
            int r = fi >> 4, c = fi & 15;
            tile4[r][c ^ (r & 15)] = v;      // XOR swizzle: conflict-free b128 r/w
        }
        __syncthreads();
        const int lane = t & 63;
        // pull this lane's entire pe row into registers (16 x float4, read LDS once)
        float4 pv[16];
#pragma unroll
        for (int i = 0; i < 16; i++) pv[i] = tile4[lane][i ^ (lane & 15)];
        const int hq = __builtin_amdgcn_readfirstlane((t >> 6) << 2);  // wave-uniform head quad
        // 4 passes, one head per pass: Wg row (64 f32) is a small uniform footprint,
        // hoisted to SGPRs once per pass, FMAs run from registers.
        for (int p = 0; p < 4; p++) {
            const int hh = __builtin_amdgcn_readfirstlane(hq + p);
            const float* wgp = Wg + (hh << 6);
            float a = bg[hh];
#pragma unroll
            for (int i = 0; i < 16; i++) {
                float4 w = *(const float4*)(wgp + i * 4);
                a += pv[i].x * w.x + pv[i].y * w.y + pv[i].z * w.z + pv[i].w * w.w;
            }
            // w = max(relu(a), 1e-6) == max(a, 1e-6); softmax(qk+log w) == w*e^qk/sum
            Wout[((long)hh << 20) + rowbase + lane] = (f16_t)fmaxf(a, 1e-6f);
        }
    }
}

// ---- final GEMM: out f32 = Yb @ Wy^T + by + x ----
__global__ __launch_bounds__(256) void gemmY_k(const bf16_t* __restrict__ A,
                                               const float* __restrict__ Bw,
                                               const float* __restrict__ bias,
                                               float* __restrict__ outp,
                                               const float* __restrict__ extra) {
    __shared__ bf16_t As[2][64][40];
    __shared__ bf16_t Bs[2][64][40];
    const int t = threadIdx.x;
    const int m0 = blockIdx.y * 64, n0 = blockIdx.x * 64;
    const int lr = t >> 2, lq = t & 3;

    auto stageA = [&](int buf, int k0) {
        const bf16_t* p = A + (long)(m0 + lr) * 1024 + k0 + lq * 8;
        *(bf16x8*)&As[buf][lr][lq * 8] = *(const bf16x8*)p;
    };
    auto stageB = [&](int buf, int k0) {
        const float* p = Bw + (long)(n0 + lr) * 1024 + k0 + lq * 8;
        float4 u0 = *(const float4*)p;
        float4 u1 = *(const float4*)(p + 4);
        bf16x8 v;
        v[0] = f2b(u0.x); v[1] = f2b(u0.y); v[2] = f2b(u0.z); v[3] = f2b(u0.w);
        v[4] = f2b(u1.x); v[5] = f2b(u1.y); v[6] = f2b(u1.z); v[7] = f2b(u1.w);
        *(bf16x8*)&Bs[buf][lr][lq * 8] = v;
    };

    const int wid = t >> 6, lane = t & 63;
    const int wm = (wid >> 1) * 32, wn = (wid & 1) * 32;
    const int ml = lane & 15, kl = (lane >> 4) * 8;
    f32x4 acc[2][2] = {};

    stageA(0, 0);
    stageB(0, 0);
    __syncthreads();
    for (int kt = 0; kt < 32; kt++) {
        const int buf = kt & 1;
        if (kt + 1 < 32) { stageA(buf ^ 1, (kt + 1) * 32); stageB(buf ^ 1, (kt + 1) * 32); }
        bf16x8 a0 = *(const bf16x8*)&As[buf][wm + ml][kl];
        bf16x8 a1 = *(const bf16x8*)&As[buf][wm + 16 + ml][kl];
        bf16x8 b0 = *(const bf16x8*)&Bs[buf][wn + ml][kl];
        bf16x8 b1 = *(const bf16x8*)&Bs[buf][wn + 16 + ml][kl];
        acc[0][0] = __builtin_amdgcn_mfma_f32_16x16x32_bf16(a0, b0, acc[0][0], 0, 0, 0);
        acc[0][1] = __builtin_amdgcn_mfma_f32_16x16x32_bf16(a0, b1, acc[0][1], 0, 0, 0);
        acc[1][0] = __builtin_amdgcn_mfma_f32_16x16x32_bf16(a1, b0, acc[1][0], 0, 0, 0);
        acc[1][1] = __builtin_amdgcn_mfma_f32_16x16x32_bf16(a1, b1, acc[1][1], 0, 0, 0);
        __syncthreads();
    }

#pragma unroll
    for (int mt = 0; mt < 2; mt++)
#pragma unroll
        for (int nt = 0; nt < 2; nt++) {
            f32x4 v = acc[mt][nt];
            const int rbase = m0 + wm + mt * 16 + ((lane >> 4) << 2);
            const int col = n0 + wn + nt * 16 + (lane & 15);
#pragma unroll
            for (int r = 0; r < 4; r++) {
                const int row = rbase + r;
                long idx = ((long)row << 10) + col;
                outp[idx] = v[r] + bias[col] + extra[idx];
            }
        }
}

// ---- fused attention: per (qtile64, head): S=QK^T, p=exp(S)*w, O=pV, O/=sum ----
__global__ __launch_bounds__(256) void attn_kernel(const bf16_t* __restrict__ Q,
                                                   const bf16_t* __restrict__ K,
                                                   const bf16_t* __restrict__ Vt,
                                                   const f16_t* __restrict__ Wf,
                                                   bf16_t* __restrict__ Y) {
    __shared__ bf16_t Qs[64][72];
    __shared__ bf16_t Ks[2][64][72];
    __shared__ bf16_t Vts[2][64][72];
    __shared__ f16_t  Ws[2][64][72];
    __shared__ bf16_t Ps[4][16][72];

    const int qt = blockIdx.x, h = blockIdx.y;
    const int t = threadIdx.x;
    const int w = t >> 6, lane = t & 63;
    const int ml = lane & 15, kq = lane >> 4;
    const int q0 = qt << 6;
    const int sr = t >> 2, sc = (t & 3) << 4;

    const bf16_t* Kh = K + ((long)h << 16);
    const bf16_t* Vh = Vt + ((long)h << 16);
    const f16_t*  Wh = Wf + ((long)h << 20) + ((long)(q0 + sr) << 10);

    {   // stage Q + tile 0
        const bf16_t* src = Q + ((long)h << 16) + ((long)(q0 + sr) << 6) + sc;
        *(bf16x8*)&Qs[sr][sc]     = *(const bf16x8*)src;
        *(bf16x8*)&Qs[sr][sc + 8] = *(const bf16x8*)(src + 8);
        const bf16_t* ks = Kh + ((long)sr << 6) + sc;
        *(bf16x8*)&Ks[0][sr][sc]     = *(const bf16x8*)ks;
        *(bf16x8*)&Ks[0][sr][sc + 8] = *(const bf16x8*)(ks + 8);
        const bf16_t* vs = Vh + ((long)sr << 10) + sc;
        *(bf16x8*)&Vts[0][sr][sc]     = *(const bf16x8*)vs;
        *(bf16x8*)&Vts[0][sr][sc + 8] = *(const bf16x8*)(vs + 8);
        const f16_t* gs = Wh + sc;
        *(f16x8*)&Ws[0][sr][sc]     = *(const f16x8*)gs;
        *(f16x8*)&Ws[0][sr][sc + 8] = *(const f16x8*)(gs + 8);
    }
    __syncthreads();

    const bf16x8 aq0 = *(const bf16x8*)&Qs[(w << 4) + ml][kq * 8];
    const bf16x8 aq1 = *(const bf16x8*)&Qs[(w << 4) + ml][32 + kq * 8];

    f32x4 O[4] = {};
    float lsum[4] = {0.f, 0.f, 0.f, 0.f};

    int buf = 0;
    for (int kt = 0; kt < 16; kt++) {
        bf16x8 rk0, rk1, rv0, rv1;
        f16x8 rw0, rw1;
        const bool pf = (kt < 15);
        if (pf) {  // issue next-tile loads early (T14): latency hides under compute
            const int k0 = (kt + 1) << 6;
            const bf16_t* ks = Kh + ((long)(k0 + sr) << 6) + sc;
            rk0 = *(const bf16x8*)ks; rk1 = *(const bf16x8*)(ks + 8);
            const bf16_t* vs = Vh + ((long)sr << 10) + k0 + sc;
            rv0 = *(const bf16x8*)vs; rv1 = *(const bf16x8*)(vs + 8);
            const f16_t* gs = Wh + k0 + sc;
            rw0 = *(const f16x8*)gs; rw1 = *(const f16x8*)(gs + 8);
        }

        // QK^T: wave tile = 16 q-rows x 64 keys
        f32x4 s[4] = {};
#pragma unroll
        for (int c = 0; c < 4; c++) {
            bf16x8 bk0 = *(const bf16x8*)&Ks[buf][(c << 4) + ml][kq * 8];
            bf16x8 bk1 = *(const bf16x8*)&Ks[buf][(c << 4) + ml][32 + kq * 8];
            s[c] = __builtin_amdgcn_mfma_f32_16x16x32_bf16(aq0, bk0, s[c], 0, 0, 0);
            s[c] = __builtin_amdgcn_mfma_f32_16x16x32_bf16(aq1, bk1, s[c], 0, 0, 0);
        }
        // p = exp(s) * w   (softmax(qk+log w) == w*e^qk/sum; no max needed: |s|<~50)
#pragma unroll
        for (int c = 0; c < 4; c++) {
#pragma unroll
            for (int r = 0; r < 4; r++) {
                float wv = (float)Ws[buf][(w << 4) + (kq << 2) + r][(c << 4) + ml];
                float p = __expf(s[c][r]) * wv;
                lsum[r] += p;
                Ps[w][(kq << 2) + r][(c << 4) + ml] = f2b(p);
            }
        }
        // PV: A = P (per-wave LDS transpose), B = Vt rows (dv)
        const bf16x8 pa0 = *(const bf16x8*)&Ps[w][ml][kq * 8];
        const bf16x8 pa1 = *(const bf16x8*)&Ps[w][ml][32 + kq * 8];
#pragma unroll
        for (int c = 0; c < 4; c++) {
            bf16x8 v0 = *(const bf16x8*)&Vts[buf][(c << 4) + ml][kq * 8];
            bf16x8 v1 = *(const bf16x8*)&Vts[buf][(c << 4) + ml][32 + kq * 8];
            O[c] = __builtin_amdgcn_mfma_f32_16x16x32_bf16(pa0, v0, O[c], 0, 0, 0);
            O[c] = __builtin_amdgcn_mfma_f32_16x16x32_bf16(pa1, v1, O[c], 0, 0, 0);
        }

        if (pf) {  // write-late staging into the other buffer
            const int nb = buf ^ 1;
            *(bf16x8*)&Ks[nb][sr][sc]      = rk0;
            *(bf16x8*)&Ks[nb][sr][sc + 8]  = rk1;
            *(bf16x8*)&Vts[nb][sr][sc]     = rv0;
            *(bf16x8*)&Vts[nb][sr][sc + 8] = rv1;
            *(f16x8*)&Ws[nb][sr][sc]       = rw0;
            *(f16x8*)&Ws[nb][sr][sc + 8]   = rw1;
        }
        __syncthreads();
        buf ^= 1;
    }

#pragma unroll
    for (int r = 0; r < 4; r++) {
        float v = lsum[r];
        v += __shfl_xor(v, 1); v += __shfl_xor(v, 2);
        v += __shfl_xor(v, 4); v += __shfl_xor(v, 8);
        lsum[r] = 1.0f / v;
    }
    const int rowb = q0 + (w << 4) + (kq << 2);
    const int colb = (h << 6) + ml;
#pragma unroll
    for (int c = 0; c < 4; c++)
#pragma unroll
        for (int r = 0; r < 4; r++)
            Y[((long)(rowb + r) << 10) + colb + (c << 4)] = f2b(O[c][r] * lsum[r]);
}

extern "C" void kernel_launch(void* const* d_in, const int* in_sizes, int n_in,
                              void* d_out, int out_size, void* d_ws, size_t ws_size,
                              hipStream_t stream) {
    const float* x  = (const float*)d_in[0];
    const float* pe = (const float*)d_in[1];
    const float* Wq = (const float*)d_in[2];
    const float* bq = (const float*)d_in[3];
    const float* Wk = (const float*)d_in[4];
    const float* bk = (const float*)d_in[5];
    const float* Wv = (const float*)d_in[6];
    const float* bv = (const float*)d_in[7];
    const float* Wg = (const float*)d_in[8];
    const float* bg = (const float*)d_in[9];
    const float* Wy = (const float*)d_in[10];
    const float* by = (const float*)d_in[11];

    char* ws = (char*)d_ws;
    f16_t*  Wf = (f16_t*)ws;                         // 32 MB
    bf16_t* Qb = (bf16_t*)(ws + (32ul << 20));       // 2 MB
    bf16_t* Kb = (bf16_t*)(ws + (34ul << 20));       // 2 MB
    bf16_t* Vb = (bf16_t*)(ws + (36ul << 20));       // 2 MB
    bf16_t* Yb = (bf16_t*)(ws + (38ul << 20));       // 2 MB

    fused_g_proj_k<<<768 + 16384, 256, 0, stream>>>(pe, Wg, bg, Wf,
                                                    x, Wq, bq, Qb, Wk, bk, Kb, Wv, bv, Vb);
    attn_kernel<<<dim3(16, 16), 256, 0, stream>>>(Qb, Kb, Vb, Wf, Yb);
    gemmY_k<<<dim3(16, 16), 256, 0, stream>>>(Yb, Wy, by, (float*)d_out, x);
}